// Round 1
// baseline (13300.562 us; speedup 1.0000x reference)
//
#include <hip/hip_runtime.h>
#include <stdint.h>

typedef __attribute__((ext_vector_type(4))) float f32x4;
typedef __attribute__((ext_vector_type(8))) short s16x8;
typedef __attribute__((ext_vector_type(4))) unsigned short u16x4;
typedef unsigned short ushort_t;

#define NN 4096

// ---------------- workspace byte offsets ----------------
#define OFF_AEXT   0ull                        // bf16 [4096][3072]   25,165,824
#define OFF_BT     25165824ull                 // bf16 [4096][3072]   25,165,824
#define OFF_IOU    50331648ull                 // f32  [4097][3072]   50,343,936
#define OFF_FX     100675584ull                // f32  [4096][1024]   16,777,216
#define OFF_FXP    117452800ull                // f32  [4096][1024]   16,777,216
#define OFF_SFC    134230016ull                // f32  [4097][1024]   16,781,312
#define OFF_CWS    151011328ull                // f32  [4096][1024]   16,777,216
#define OFF_NODES  167788544ull                // u32  [4096]
#define OFF_START  (OFF_NODES + 16384ull)      // u32  [4100]
#define OFF_NLEV   (OFF_START + 16400ull)      // u32  [1]
#define OFF_CNT    (OFF_NLEV + 1008ull)        // u32  [4100*8]

// ---------------- helpers ----------------
__device__ __forceinline__ ushort_t f2bf(float f) {
    unsigned u = __float_as_uint(f);
    unsigned r = (u + 0x7FFFu + ((u >> 16) & 1u)) >> 16;
    return (ushort_t)r;
}
__device__ __forceinline__ float bf2f(ushort_t b) {
    return __uint_as_float(((unsigned)b) << 16);
}
__device__ __forceinline__ float sigm(float x) { return 1.0f / (1.0f + __expf(-x)); }
__device__ __forceinline__ float tanh_f(float x) {
    float e = __expf(-2.0f * fabsf(x));
    float t = (1.0f - e) / (1.0f + e);
    return copysignf(t, x);
}
// agent-scope (LLC) load/store: bypass possibly-stale L1/L2
__device__ __forceinline__ float ld_dev(const float* p) {
    return __hip_atomic_load(p, __ATOMIC_RELAXED, __HIP_MEMORY_SCOPE_AGENT);
}
__device__ __forceinline__ unsigned ld_devu(const unsigned* p) {
    return __hip_atomic_load(p, __ATOMIC_RELAXED, __HIP_MEMORY_SCOPE_AGENT);
}
__device__ __forceinline__ void st_dev(float* p, float v) {
    __hip_atomic_store(p, v, __ATOMIC_RELAXED, __HIP_MEMORY_SCOPE_AGENT);
}
__device__ __forceinline__ void gload16(const void* g, void* l) {
    __builtin_amdgcn_global_load_lds((const __attribute__((address_space(1))) unsigned*)g,
                                     (__attribute__((address_space(3))) unsigned*)l, 16, 0, 0);
}
__device__ __forceinline__ f32x4 shx4(f32x4 v, int m) {
    f32x4 r;
    r[0] = __shfl_xor(v[0], m); r[1] = __shfl_xor(v[1], m);
    r[2] = __shfl_xor(v[2], m); r[3] = __shfl_xor(v[3], m);
    return r;
}

// ---------------- kernel 1: build Aext (split-bf16 of inputs) ----------------
__global__ void k_build_aext(const float* __restrict__ inputs, ushort_t* __restrict__ aext) {
    int t = blockIdx.x;
    int k0 = threadIdx.x * 4;
    f32x4 v = *(const f32x4*)(inputs + (size_t)t * 1024 + k0);
    u16x4 hi, lo;
#pragma unroll
    for (int j = 0; j < 4; ++j) {
        float f = v[j];
        ushort_t hb = f2bf(f);
        float fr = f - bf2f(hb);
        hi[j] = hb; lo[j] = f2bf(fr);
    }
    size_t base = (size_t)t * 3072;
    *(u16x4*)(aext + base + k0)        = hi;
    *(u16x4*)(aext + base + 1024 + k0) = lo;
    *(u16x4*)(aext + base + 2048 + k0) = hi;
}

// ---------------- kernel 2: build B^T ext (transpose + split-bf16 of [Wioux|Wfx]) ----------------
__global__ void k_build_bt(const float* __restrict__ Wioux, const float* __restrict__ Wfx,
                           ushort_t* __restrict__ bt) {
    __shared__ float ld[64][65];
    int k0 = blockIdx.x * 64, n0 = blockIdx.y * 64;
    const float* src; int scol, sstr;
    if (n0 < 3072) { src = Wioux; scol = n0; sstr = 3072; }
    else           { src = Wfx;   scol = n0 - 3072; sstr = 1024; }
    int tid = threadIdx.x;
    int nl = tid & 63, kh = tid >> 6;
#pragma unroll
    for (int i = 0; i < 16; ++i) {
        int kl = kh * 16 + i;
        ld[kl][nl] = src[(size_t)(k0 + kl) * sstr + scol + nl];
    }
    __syncthreads();
    int nl2 = tid >> 2, kq = tid & 3;
#pragma unroll
    for (int i2 = 0; i2 < 4; ++i2) {
        int kb = kq * 16 + i2 * 4;
        u16x4 hi, lo;
#pragma unroll
        for (int j = 0; j < 4; ++j) {
            float f = ld[kb + j][nl2];
            ushort_t hb = f2bf(f);
            hi[j] = hb; lo[j] = f2bf(f - bf2f(hb));
        }
        size_t ob = (size_t)(n0 + nl2) * 3072 + k0 + kb;
        *(u16x4*)(bt + ob)        = hi;
        *(u16x4*)(bt + ob + 1024) = hi;
        *(u16x4*)(bt + ob + 2048) = lo;
    }
}

// ---------------- kernel 3: level schedule (single block, 1 wave) ----------------
__global__ void k_sched(const int* __restrict__ parent, unsigned* __restrict__ g_nodes,
                        unsigned* __restrict__ g_start, unsigned* __restrict__ g_nlev) {
    __shared__ unsigned lvl[4097];
    __shared__ ushort_t par[4096];
    __shared__ unsigned cnts[4100];
    __shared__ unsigned curs[4100];
    int lane = threadIdx.x; // 0..63
    for (int i = lane; i < 4097; i += 64) lvl[i] = 0;
    for (int i = lane; i < 4100; i += 64) cnts[i] = 0;
    for (int i = lane; i < 4096; i += 64) par[i] = (ushort_t)parent[i];
    __syncthreads();
    for (int base = 0; base < 4096; base += 64) {
        int t = base + lane;
        int p = par[t];
        unsigned prev = lvl[t];
        while (true) {
            atomicMax(&lvl[p], prev + 1);
            __syncthreads();
            unsigned cur = lvl[t];
            int ch = (cur != prev);
            prev = cur;
            if (!__any(ch)) break;
            __syncthreads();
        }
        __syncthreads();
    }
    unsigned maxl = 0;
    for (int t = lane; t < 4096; t += 64) {
        unsigned l = lvl[t];
        maxl = max(maxl, l);
        atomicAdd(&cnts[l], 1u);
    }
#pragma unroll
    for (int o = 32; o; o >>= 1) maxl = max(maxl, (unsigned)__shfl_xor((int)maxl, o));
    __syncthreads();
    unsigned carry = 0;
    for (int base = 0; base < 4100; base += 64) {
        int i = base + lane;
        unsigned v = (i < 4100) ? cnts[i] : 0u;
        unsigned orig = v;
#pragma unroll
        for (int o = 1; o < 64; o <<= 1) {
            unsigned n = __shfl_up(v, o);
            if (lane >= o) v += n;
        }
        unsigned excl = carry + v - orig;
        if (i < 4100) { curs[i] = excl; g_start[i] = excl; }
        carry += (unsigned)__shfl((int)v, 63);
    }
    __syncthreads();
    for (int t = lane; t < 4096; t += 64) {
        unsigned slot = atomicAdd(&curs[lvl[t]], 1u);
        g_nodes[slot] = (unsigned)t;
    }
    if (lane == 0) *g_nlev = maxl + 1;
}

// ---------------- kernel 4: split-bf16 MFMA GEMM  C[4096][4096] = Aext @ Bext^T ----------------
__launch_bounds__(256)
__global__ void k_gemm(const ushort_t* __restrict__ A, const ushort_t* __restrict__ B,
                       const float* __restrict__ bioux, const float* __restrict__ biouh,
                       const float* __restrict__ bfx,
                       float* __restrict__ iou, float* __restrict__ fx) {
    __shared__ ushort_t As[128 * 32];
    __shared__ ushort_t Bs[128 * 32];
    int tid = threadIdx.x;
    int w = tid >> 6, l = tid & 63;
    int m0 = blockIdx.x * 128, n0 = blockIdx.y * 128;
    int wr = w >> 1, wc = w & 1;
    f32x4 acc[4][4];
    f32x4 z = {0.f, 0.f, 0.f, 0.f};
#pragma unroll
    for (int a = 0; a < 4; ++a)
#pragma unroll
        for (int b = 0; b < 4; ++b) acc[a][b] = z;

    for (int k0 = 0; k0 < 3072; k0 += 32) {
        __syncthreads();
#pragma unroll
        for (int i = 0; i < 2; ++i) {
            int qb = i * 256 + w * 64;
            int q = qb + l;
            int row = q >> 2, ksp = q & 3;
            int ksl = ksp ^ (row & 3);
            gload16(A + (size_t)(m0 + row) * 3072 + k0 + ksl * 8, (char*)As + qb * 16);
            gload16(B + (size_t)(n0 + row) * 3072 + k0 + ksl * 8, (char*)Bs + qb * 16);
        }
        __syncthreads();
        s16x8 av[4], bv[4];
#pragma unroll
        for (int fr = 0; fr < 4; ++fr) {
            int ra = wr * 64 + fr * 16 + (l & 15);
            av[fr] = *(const s16x8*)((const char*)As + ra * 64 + ((((l >> 4) ^ (ra & 3)) & 3) << 4));
            int rb = wc * 64 + fr * 16 + (l & 15);
            bv[fr] = *(const s16x8*)((const char*)Bs + rb * 64 + ((((l >> 4) ^ (rb & 3)) & 3) << 4));
        }
#pragma unroll
        for (int fr = 0; fr < 4; ++fr)
#pragma unroll
            for (int fc = 0; fc < 4; ++fc)
                acc[fr][fc] = __builtin_amdgcn_mfma_f32_16x16x32_bf16(av[fr], bv[fc], acc[fr][fc], 0, 0, 0);
    }
#pragma unroll
    for (int fc = 0; fc < 4; ++fc) {
        int col = n0 + wc * 64 + fc * 16 + (l & 15);
        bool isiou = col < 3072;
        float badd = isiou ? (bioux[col] + biouh[col]) : bfx[col - 3072];
#pragma unroll
        for (int fr = 0; fr < 4; ++fr) {
            int r0 = m0 + wr * 64 + fr * 16 + ((l >> 4) << 2);
#pragma unroll
            for (int jj = 0; jj < 4; ++jj) {
                float v2 = acc[fr][fc][jj] + badd;
                if (isiou) iou[(size_t)(r0 + jj) * 3072 + col] = v2;
                else       fx[(size_t)(r0 + jj) * 1024 + (col - 3072)] = v2;
            }
        }
    }
}

// ---------------- kernel 5: fxp = bfh + fx[parent]; zero sum_fc and counters ----------------
__global__ void k_fxp(const int* __restrict__ parent, const float* __restrict__ fx,
                      const float* __restrict__ bfh, float* __restrict__ fxp,
                      float* __restrict__ sfc, unsigned* __restrict__ cnt) {
    int t = blockIdx.x;
    int d = threadIdx.x * 4;
    f32x4 z = {0.f, 0.f, 0.f, 0.f};
    if (t < 4096) {
        int p = parent[t];
        f32x4 add = (p < 4096) ? *(const f32x4*)(fx + ((size_t)p << 10) + d) : z;
        f32x4 bv = *(const f32x4*)(bfh + d);
        *(f32x4*)(fxp + ((size_t)t << 10) + d) = bv + add;
        *(f32x4*)(sfc + ((size_t)t << 10) + d) = z;
    } else {
        *(f32x4*)(sfc + ((size_t)t << 10) + d) = z;
        for (int i = threadIdx.x; i < 4100 * 8; i += 256) cnt[i] = 0u;
    }
}

// ---------------- kernel 6: persistent level-synchronous Tree-LSTM ----------------
__launch_bounds__(256, 1)
__global__ void k_tree(const float* __restrict__ Wiouh, const float* __restrict__ Wfh,
                       const int* __restrict__ parent,
                       float* iou, float* sfc, float* cws,
                       const float* __restrict__ fxp,
                       const unsigned* __restrict__ g_nodes, const unsigned* __restrict__ g_start,
                       const unsigned* __restrict__ g_nlev,
                       unsigned* cnt, float* outf) {
    __shared__ f32x4 hbuf4[16 * 256];        // 64KB, swizzled h staging (16 nodes)
    __shared__ f32x4 part[16][4][16];        // 16KB partial sums
    __shared__ ushort_t nd[4096];            // level-ordered node ids
    __shared__ unsigned st[4100];            // level start offsets
    __shared__ int bailflag;
    char* hbufc = (char*)hbuf4;

    int tid = threadIdx.x;
    int w = tid >> 6, l = tid & 63;
    int d0 = blockIdx.x << 2;                // this block owns h-dims d0..d0+3
    int rb = tid >> 2, cq = tid & 3;         // 64 row-blocks x 4 col-quads
    int sw2 = (rb >> 1) & 3;

    if (tid == 0) bailflag = 0;
    for (int i = tid; i < 4096; i += 256) nd[i] = (ushort_t)g_nodes[i];
    for (int i = tid; i < 4100; i += 256) st[i] = g_start[i];

    // register-resident weights: 16 rows x 4 cols per thread
    f32x4 wv[16];
    {
        const float* wb; size_t strd; int coff;
        if (cq < 3) { wb = Wiouh; strd = 3072; coff = cq * 1024 + d0; }
        else        { wb = Wfh;   strd = 1024; coff = d0; }
#pragma unroll
        for (int m = 0; m < 16; ++m)
            wv[m] = *(const f32x4*)(wb + (size_t)(rb * 16 + m) * strd + coff);
    }
    unsigned nlev = *g_nlev;
    if (nlev > 4096u) nlev = 4096u;
    __syncthreads();

    bool bailed = false;
    for (unsigned L = 0; L < nlev; ++L) {
        unsigned s0 = st[L], s1 = st[L + 1];
        if (s0 > 4096u) s0 = 4096u;
        if (s1 > 4096u) s1 = 4096u;
        if (s1 < s0) s1 = s0;
        int m = (int)(s1 - s0);

        // ---- phase E: gate nonlinearities for this level's nodes, own dims ----
        for (int idx = tid; idx < (m << 2); idx += 256) {
            int s = idx >> 2, j = idx & 3;
            int t = nd[s0 + s];
            int d = d0 + j;
            size_t b3 = (size_t)t * 3072 + d;
            float vi = ld_dev(iou + b3);
            float vo = ld_dev(iou + b3 + 1024);
            float vu = ld_dev(iou + b3 + 2048);
            float sf = ld_dev(sfc + ((size_t)t << 10) + d);
            float cc = sigm(vi) * tanh_f(vu) + sf;
            float hh = sigm(vo) * tanh_f(cc);
            cws[((size_t)t << 10) + d] = cc;
            st_dev(outf + ((size_t)t << 10) + d, hh);
        }
        __syncthreads();
        if (tid == 0)
            __hip_atomic_fetch_add(cnt + ((size_t)L << 3) + (blockIdx.x & 7), 1u,
                                   __ATOMIC_RELAXED, __HIP_MEMORY_SCOPE_AGENT);
        if (!bailed && tid < 8) {
            const unsigned* cp = cnt + ((size_t)L << 3) + tid;
            int sp = 0;
            while (ld_devu(cp) < 32u) {
                if (++sp > (1 << 18)) { bailflag = 1; break; }
            }
        }
        __syncthreads();
        bailed = bailed || (bailflag != 0);

        // ---- phase M: matvec contributions to parents, 16-node chunks ----
        for (int ch = 0; ch < m; ch += 16) {
            int cm = min(16, m - ch);
            // stage full h vectors into swizzled LDS
            int items = cm << 10;
            for (int q = tid; q < items; q += 256) {
                int s = q >> 10, r = q & 1023;
                int t = nd[s0 + ch + s];
                float hv = ld_dev(outf + ((size_t)t << 10) + r);
                unsigned byte = (unsigned)(s << 12) + (((unsigned)(r << 2)) ^ ((((unsigned)r >> 5) & 3u) << 4));
                *(float*)(hbufc + byte) = hv;
            }
            __syncthreads();
            // MAC: each thread 16 rows x 4 cols per node
            f32x4 acc[16];
            f32x4 z = {0.f, 0.f, 0.f, 0.f};
#pragma unroll
            for (int s = 0; s < 16; ++s) acc[s] = z;
#pragma unroll
            for (int s = 0; s < 16; ++s) {
                if (s < cm) {
#pragma unroll
                    for (int ip = 0; ip < 4; ++ip) {
                        f32x4 h4 = *(const f32x4*)(hbufc + (s << 12) + (rb << 6) + (((ip ^ sw2) & 3) << 4));
#pragma unroll
                        for (int jj = 0; jj < 4; ++jj)
                            acc[s] += wv[ip * 4 + jj] * h4[jj];
                    }
                }
            }
            // partial reduce (within-wave over 4 row-blocks), stash to LDS
#pragma unroll
            for (int s = 0; s < 16; ++s) {
                if (s < cm) {
                    f32x4 v = acc[s];
                    v += shx4(v, 4);
                    v += shx4(v, 8);
                    if ((l & 12) == 0) part[s][cq][(w << 2) + (l >> 4)] = v;
                }
            }
            __syncthreads();
            // final reduce + scatter updates (one thread per (node, col))
            if (tid < (cm << 4)) {
                int s = tid >> 4, c = tid & 15;
                int cqq = c >> 2, j = c & 3;
                float sum = 0.f;
#pragma unroll
                for (int rq = 0; rq < 16; ++rq) sum += part[s][cqq][(rq + tid) & 15][j];
                int t = nd[s0 + ch + s];
                int p = parent[t];
                if (c < 12) {
                    atomicAdd(iou + (size_t)p * 3072 + cqq * 1024 + d0 + j, sum);
                } else {
                    int d = d0 + j;
                    float fv = sigm(sum + fxp[((size_t)t << 10) + d]);
                    float cv = cws[((size_t)t << 10) + d];
                    atomicAdd(sfc + ((size_t)p << 10) + d, fv * cv);
                }
            }
            __syncthreads();
        }
    }
}

// ---------------- launcher ----------------
extern "C" void kernel_launch(void* const* d_in, const int* in_sizes, int n_in,
                              void* d_out, int out_size, void* d_ws, size_t ws_size,
                              hipStream_t stream) {
    const float* inputs = (const float*)d_in[0];
    const int* parent   = (const int*)d_in[1];
    const float* Wioux  = (const float*)d_in[2];
    const float* bioux  = (const float*)d_in[3];
    const float* Wiouh  = (const float*)d_in[4];
    const float* biouh  = (const float*)d_in[5];
    const float* Wfx    = (const float*)d_in[6];
    const float* bfx    = (const float*)d_in[7];
    const float* Wfh    = (const float*)d_in[8];
    const float* bfh    = (const float*)d_in[9];
    float* outf = (float*)d_out;
    char* ws = (char*)d_ws;

    ushort_t* aext   = (ushort_t*)(ws + OFF_AEXT);
    ushort_t* bt     = (ushort_t*)(ws + OFF_BT);
    float* iou       = (float*)(ws + OFF_IOU);
    float* fx        = (float*)(ws + OFF_FX);
    float* fxp       = (float*)(ws + OFF_FXP);
    float* sfc       = (float*)(ws + OFF_SFC);
    float* cws       = (float*)(ws + OFF_CWS);
    unsigned* g_nodes = (unsigned*)(ws + OFF_NODES);
    unsigned* g_start = (unsigned*)(ws + OFF_START);
    unsigned* g_nlev  = (unsigned*)(ws + OFF_NLEV);
    unsigned* cnt     = (unsigned*)(ws + OFF_CNT);

    k_build_aext<<<dim3(4096), dim3(256), 0, stream>>>(inputs, aext);
    k_build_bt<<<dim3(16, 64), dim3(256), 0, stream>>>(Wioux, Wfx, bt);
    k_sched<<<dim3(1), dim3(64), 0, stream>>>(parent, g_nodes, g_start, g_nlev);
    k_gemm<<<dim3(32, 32), dim3(256), 0, stream>>>(aext, bt, bioux, biouh, bfx, iou, fx);
    k_fxp<<<dim3(4097), dim3(256), 0, stream>>>(parent, fx, bfh, fxp, sfc, cnt);
    k_tree<<<dim3(256), dim3(256), 0, stream>>>(Wiouh, Wfh, parent, iou, sfc, cws, fxp,
                                                g_nodes, g_start, g_nlev, cnt, outf);
}

// Round 2
// 12759.855 us; speedup vs baseline: 1.0424x; 1.0424x over previous
//
#include <hip/hip_runtime.h>
#include <stdint.h>

typedef __attribute__((ext_vector_type(4))) float f32x4;
typedef __attribute__((ext_vector_type(8))) short s16x8;
typedef __attribute__((ext_vector_type(4))) unsigned short u16x4;
typedef unsigned short ushort_t;

#define NN 4096
#define NBLK 128

// ---------------- workspace byte offsets ----------------
#define OFF_AEXT   0ull                        // bf16 [4096][3072]
#define OFF_BT     25165824ull                 // bf16 [4096][3072]
#define OFF_IOU    50331648ull                 // f32  [4097][3072]
#define OFF_FX     100675584ull                // f32  [4096][1024]
#define OFF_FXP    117452800ull                // f32  [4096][1024]
#define OFF_SFC    134230016ull                // f32  [4097][1024]
#define OFF_CWS    151011328ull                // f32  [4096][1024]
#define OFF_NODES  167788544ull                // u32  [4096]
#define OFF_START  (OFF_NODES + 16384ull)      // u32  [4100]
#define OFF_NLEV   (OFF_START + 16400ull)      // u32  [1]
#define OFF_CNT    (OFF_NLEV + 1008ull)        // u32  [4100]

// ---------------- helpers ----------------
__device__ __forceinline__ ushort_t f2bf(float f) {
    unsigned u = __float_as_uint(f);
    unsigned r = (u + 0x7FFFu + ((u >> 16) & 1u)) >> 16;
    return (ushort_t)r;
}
__device__ __forceinline__ float bf2f(ushort_t b) {
    return __uint_as_float(((unsigned)b) << 16);
}
__device__ __forceinline__ float sigm(float x) { return 1.0f / (1.0f + __expf(-x)); }
__device__ __forceinline__ float tanh_f(float x) {
    float e = __expf(-2.0f * fabsf(x));
    float t = (1.0f - e) / (1.0f + e);
    return copysignf(t, x);
}
// agent-scope (LLC) ops: only for cross-block data (h, barrier counter)
__device__ __forceinline__ unsigned long long ld_dev64(const void* p) {
    return __hip_atomic_load((const unsigned long long*)p, __ATOMIC_RELAXED,
                             __HIP_MEMORY_SCOPE_AGENT);
}
__device__ __forceinline__ unsigned ld_devu(const unsigned* p) {
    return __hip_atomic_load(p, __ATOMIC_RELAXED, __HIP_MEMORY_SCOPE_AGENT);
}
__device__ __forceinline__ void st_dev(float* p, float v) {
    __hip_atomic_store(p, v, __ATOMIC_RELAXED, __HIP_MEMORY_SCOPE_AGENT);
}
// workgroup-scope atomic add on block-private global data: executes in XCD L2
__device__ __forceinline__ void atomAddWg(float* p, float v) {
    __hip_atomic_fetch_add(p, v, __ATOMIC_RELAXED, __HIP_MEMORY_SCOPE_WORKGROUP);
}
__device__ __forceinline__ void gload16(const void* g, void* l) {
    __builtin_amdgcn_global_load_lds((const __attribute__((address_space(1))) unsigned*)g,
                                     (__attribute__((address_space(3))) unsigned*)l, 16, 0, 0);
}
__device__ __forceinline__ f32x4 shx4(f32x4 v, int m) {
    f32x4 r;
    r[0] = __shfl_xor(v[0], m); r[1] = __shfl_xor(v[1], m);
    r[2] = __shfl_xor(v[2], m); r[3] = __shfl_xor(v[3], m);
    return r;
}

// ---------------- kernel 1: build Aext (split-bf16 of inputs) ----------------
__global__ void k_build_aext(const float* __restrict__ inputs, ushort_t* __restrict__ aext) {
    int t = blockIdx.x;
    int k0 = threadIdx.x * 4;
    f32x4 v = *(const f32x4*)(inputs + (size_t)t * 1024 + k0);
    u16x4 hi, lo;
#pragma unroll
    for (int j = 0; j < 4; ++j) {
        float f = v[j];
        ushort_t hb = f2bf(f);
        float fr = f - bf2f(hb);
        hi[j] = hb; lo[j] = f2bf(fr);
    }
    size_t base = (size_t)t * 3072;
    *(u16x4*)(aext + base + k0)        = hi;
    *(u16x4*)(aext + base + 1024 + k0) = lo;
    *(u16x4*)(aext + base + 2048 + k0) = hi;
}

// ---------------- kernel 2: build B^T ext (transpose + split-bf16 of [Wioux|Wfx]) ----------------
__global__ void k_build_bt(const float* __restrict__ Wioux, const float* __restrict__ Wfx,
                           ushort_t* __restrict__ bt) {
    __shared__ float ld[64][65];
    int k0 = blockIdx.x * 64, n0 = blockIdx.y * 64;
    const float* src; int scol, sstr;
    if (n0 < 3072) { src = Wioux; scol = n0; sstr = 3072; }
    else           { src = Wfx;   scol = n0 - 3072; sstr = 1024; }
    int tid = threadIdx.x;
    int nl = tid & 63, kh = tid >> 6;
#pragma unroll
    for (int i = 0; i < 16; ++i) {
        int kl = kh * 16 + i;
        ld[kl][nl] = src[(size_t)(k0 + kl) * sstr + scol + nl];
    }
    __syncthreads();
    int nl2 = tid >> 2, kq = tid & 3;
#pragma unroll
    for (int i2 = 0; i2 < 4; ++i2) {
        int kb = kq * 16 + i2 * 4;
        u16x4 hi, lo;
#pragma unroll
        for (int j = 0; j < 4; ++j) {
            float f = ld[kb + j][nl2];
            ushort_t hb = f2bf(f);
            hi[j] = hb; lo[j] = f2bf(f - bf2f(hb));
        }
        size_t ob = (size_t)(n0 + nl2) * 3072 + k0 + kb;
        *(u16x4*)(bt + ob)        = hi;
        *(u16x4*)(bt + ob + 1024) = hi;
        *(u16x4*)(bt + ob + 2048) = lo;
    }
}

// ---------------- kernel 3: level schedule (single block, 1 wave) ----------------
__global__ void k_sched(const int* __restrict__ parent, unsigned* __restrict__ g_nodes,
                        unsigned* __restrict__ g_start, unsigned* __restrict__ g_nlev) {
    __shared__ unsigned lvl[4097];
    __shared__ ushort_t par[4096];
    __shared__ unsigned cnts[4100];
    __shared__ unsigned curs[4100];
    int lane = threadIdx.x; // 0..63
    for (int i = lane; i < 4097; i += 64) lvl[i] = 0;
    for (int i = lane; i < 4100; i += 64) cnts[i] = 0;
    for (int i = lane; i < 4096; i += 64) par[i] = (ushort_t)parent[i];
    __syncthreads();
    for (int base = 0; base < 4096; base += 64) {
        int t = base + lane;
        int p = par[t];
        unsigned prev = lvl[t];
        while (true) {
            atomicMax(&lvl[p], prev + 1);
            __syncthreads();
            unsigned cur = lvl[t];
            int ch = (cur != prev);
            prev = cur;
            if (!__any(ch)) break;
            __syncthreads();
        }
        __syncthreads();
    }
    unsigned maxl = 0;
    for (int t = lane; t < 4096; t += 64) {
        unsigned l = lvl[t];
        maxl = max(maxl, l);
        atomicAdd(&cnts[l], 1u);
    }
#pragma unroll
    for (int o = 32; o; o >>= 1) maxl = max(maxl, (unsigned)__shfl_xor((int)maxl, o));
    __syncthreads();
    unsigned carry = 0;
    for (int base = 0; base < 4100; base += 64) {
        int i = base + lane;
        unsigned v = (i < 4100) ? cnts[i] : 0u;
        unsigned orig = v;
#pragma unroll
        for (int o = 1; o < 64; o <<= 1) {
            unsigned n = __shfl_up(v, o);
            if (lane >= o) v += n;
        }
        unsigned excl = carry + v - orig;
        if (i < 4100) { curs[i] = excl; g_start[i] = excl; }
        carry += (unsigned)__shfl((int)v, 63);
    }
    __syncthreads();
    for (int t = lane; t < 4096; t += 64) {
        unsigned slot = atomicAdd(&curs[lvl[t]], 1u);
        g_nodes[slot] = (unsigned)t;
    }
    if (lane == 0) *g_nlev = maxl + 1;
}

// ---------------- kernel 4: split-bf16 MFMA GEMM  C[4096][4096] = Aext @ Bext^T ----------------
__launch_bounds__(256)
__global__ void k_gemm(const ushort_t* __restrict__ A, const ushort_t* __restrict__ B,
                       const float* __restrict__ bioux, const float* __restrict__ biouh,
                       const float* __restrict__ bfx,
                       float* __restrict__ iou, float* __restrict__ fx) {
    __shared__ ushort_t As[128 * 32];
    __shared__ ushort_t Bs[128 * 32];
    int tid = threadIdx.x;
    int w = tid >> 6, l = tid & 63;
    int m0 = blockIdx.x * 128, n0 = blockIdx.y * 128;
    int wr = w >> 1, wc = w & 1;
    f32x4 acc[4][4];
    f32x4 z = {0.f, 0.f, 0.f, 0.f};
#pragma unroll
    for (int a = 0; a < 4; ++a)
#pragma unroll
        for (int b = 0; b < 4; ++b) acc[a][b] = z;

    for (int k0 = 0; k0 < 3072; k0 += 32) {
        __syncthreads();
#pragma unroll
        for (int i = 0; i < 2; ++i) {
            int qb = i * 256 + w * 64;
            int q = qb + l;
            int row = q >> 2, ksp = q & 3;
            int ksl = ksp ^ (row & 3);
            gload16(A + (size_t)(m0 + row) * 3072 + k0 + ksl * 8, (char*)As + qb * 16);
            gload16(B + (size_t)(n0 + row) * 3072 + k0 + ksl * 8, (char*)Bs + qb * 16);
        }
        __syncthreads();
        s16x8 av[4], bv[4];
#pragma unroll
        for (int fr = 0; fr < 4; ++fr) {
            int ra = wr * 64 + fr * 16 + (l & 15);
            av[fr] = *(const s16x8*)((const char*)As + ra * 64 + ((((l >> 4) ^ (ra & 3)) & 3) << 4));
            int rb = wc * 64 + fr * 16 + (l & 15);
            bv[fr] = *(const s16x8*)((const char*)Bs + rb * 64 + ((((l >> 4) ^ (rb & 3)) & 3) << 4));
        }
#pragma unroll
        for (int fr = 0; fr < 4; ++fr)
#pragma unroll
            for (int fc = 0; fc < 4; ++fc)
                acc[fr][fc] = __builtin_amdgcn_mfma_f32_16x16x32_bf16(av[fr], bv[fc], acc[fr][fc], 0, 0, 0);
    }
#pragma unroll
    for (int fc = 0; fc < 4; ++fc) {
        int col = n0 + wc * 64 + fc * 16 + (l & 15);
        bool isiou = col < 3072;
        float badd = isiou ? (bioux[col] + biouh[col]) : bfx[col - 3072];
#pragma unroll
        for (int fr = 0; fr < 4; ++fr) {
            int r0 = m0 + wr * 64 + fr * 16 + ((l >> 4) << 2);
#pragma unroll
            for (int jj = 0; jj < 4; ++jj) {
                float v2 = acc[fr][fc][jj] + badd;
                if (isiou) iou[(size_t)(r0 + jj) * 3072 + col] = v2;
                else       fx[(size_t)(r0 + jj) * 1024 + (col - 3072)] = v2;
            }
        }
    }
}

// ---------------- kernel 5: fxp = bfh + fx[parent]; zero sum_fc and counters ----------------
__global__ void k_fxp(const int* __restrict__ parent, const float* __restrict__ fx,
                      const float* __restrict__ bfh, float* __restrict__ fxp,
                      float* __restrict__ sfc, unsigned* __restrict__ cnt) {
    int t = blockIdx.x;
    int d = threadIdx.x * 4;
    f32x4 z = {0.f, 0.f, 0.f, 0.f};
    if (t < 4096) {
        int p = parent[t];
        f32x4 add = (p < 4096) ? *(const f32x4*)(fx + ((size_t)p << 10) + d) : z;
        f32x4 bv = *(const f32x4*)(bfh + d);
        *(f32x4*)(fxp + ((size_t)t << 10) + d) = bv + add;
        *(f32x4*)(sfc + ((size_t)t << 10) + d) = z;
    } else {
        *(f32x4*)(sfc + ((size_t)t << 10) + d) = z;
        for (int i = threadIdx.x; i < 4100; i += 256) cnt[i] = 0u;
    }
}

// ---------------- kernel 6: persistent level-synchronous Tree-LSTM ----------------
// 128 blocks x 512 threads; block b owns h-dims d0=8b..8b+7.
// Block-private (L2-cached, workgroup-scope): iou, sfc, cws. Cross-block (LLC): outf(h), cnt.
__launch_bounds__(512, 2)
__global__ void k_tree(const float* __restrict__ Wiouh, const float* __restrict__ Wfh,
                       const int* __restrict__ parent,
                       float* iou, float* sfc, float* cws,
                       const float* __restrict__ fxp,
                       const unsigned* __restrict__ g_nodes, const unsigned* __restrict__ g_start,
                       const unsigned* __restrict__ g_nlev,
                       unsigned* cnt, float* outf) {
    __shared__ char hbufc[8 * 4096];         // 32KB swizzled h staging (8 nodes)
    __shared__ f32x4 part[8][8][8];          // 8KB  [node][wave][colquad]
    __shared__ ushort_t nd[4096];            // level-ordered node ids
    __shared__ ushort_t par[4096];           // parent ids
    __shared__ unsigned st[4100];            // level start offsets
    __shared__ int bailflag;

    int tid = threadIdx.x;
    int w = tid >> 6;                        // wave 0..7
    int d0 = blockIdx.x << 3;                // own 8 h-dims
    int rb = tid >> 3, cq = tid & 7;         // 64 row-blocks x 8 col-quads

    if (tid == 0) bailflag = 0;
    for (int i = tid; i < 4096; i += 512) nd[i] = (ushort_t)g_nodes[i];
    for (int i = tid; i < 4096; i += 512) par[i] = (ushort_t)parent[i];
    for (int i = tid; i < 4100; i += 512) st[i] = g_start[i];

    // register-resident weights: 16 rows x 4 cols per thread (64 VGPRs)
    // cols: cq<6 -> iou gate (cq>>1), dim block (cq&1)*4 ; cq>=6 -> f dims (cq-6)*4
    f32x4 wv[16];
    {
        const float* wb; size_t strd; int coff;
        if (cq < 6) { wb = Wiouh; strd = 3072; coff = (cq >> 1) * 1024 + d0 + (cq & 1) * 4; }
        else        { wb = Wfh;   strd = 1024; coff = d0 + (cq - 6) * 4; }
#pragma unroll
        for (int m16 = 0; m16 < 16; ++m16)
            wv[m16] = *(const f32x4*)(wb + (size_t)(rb * 16 + m16) * strd + coff);
    }
    unsigned nlev = *g_nlev;
    if (nlev > 4096u) nlev = 4096u;
    __syncthreads();

    bool bailed = false;
    for (unsigned L = 0; L < nlev; ++L) {
        unsigned s0 = st[L], s1 = st[L + 1];
        if (s0 > 4096u) s0 = 4096u;
        if (s1 > 4096u) s1 = 4096u;
        if (s1 < s0) s1 = s0;
        int m = (int)(s1 - s0);

        // ---- phase E: gates for this level's nodes, own 8 dims (plain cached loads) ----
        for (int idx = tid; idx < (m << 3); idx += 512) {
            int s = idx >> 3, j = idx & 7;
            int t = nd[s0 + s];
            int d = d0 + j;
            size_t b3 = (size_t)t * 3072 + d;
            float vi = iou[b3];
            float vo = iou[b3 + 1024];
            float vu = iou[b3 + 2048];
            float sf = sfc[((size_t)t << 10) + d];
            float cc = sigm(vi) * tanh_f(vu) + sf;
            float hh = sigm(vo) * tanh_f(cc);
            cws[((size_t)t << 10) + d] = cc;
            st_dev(outf + ((size_t)t << 10) + d, hh);   // publish h (LLC)
        }
        __syncthreads();   // drains all waves' h stores (vmcnt(0) before s_barrier)

        // ---- barrier: one add + one poller per block, sleep backoff ----
        if (tid == 0) {
            __hip_atomic_fetch_add(cnt + L, 1u, __ATOMIC_RELEASE, __HIP_MEMORY_SCOPE_AGENT);
            if (!bailed) {
                int sp = 0;
                while (ld_devu(cnt + L) < (unsigned)NBLK) {
                    __builtin_amdgcn_s_sleep(2);
                    if (++sp > (1 << 14)) { bailflag = 1; break; }
                }
            }
        }
        __syncthreads();
        bailed = bailed || (bailflag != 0);

        // ---- phase M: matvec contributions to parents, 8-node chunks ----
        for (int ch = 0; ch < m; ch += 8) {
            int cm = min(8, m - ch);
            // stage h into swizzled LDS (8B agent loads; bijective swizzle B^=((B>>6)&3)<<4)
            int items = cm << 9;   // cm*512 u64 pairs
            for (int q = tid; q < items; q += 512) {
                int s = q >> 9, r = q & 511;
                int t = nd[s0 + ch + s];
                unsigned long long v = ld_dev64(outf + ((size_t)t << 10) + (r << 1));
                *(unsigned long long*)(hbufc + (s << 12) + ((r << 3) ^ (((r >> 3) & 3) << 4))) = v;
            }
            __syncthreads();
            // MAC: per thread 16 rows x 4 cols per node
            f32x4 acc[8];
            f32x4 z = {0.f, 0.f, 0.f, 0.f};
#pragma unroll
            for (int s = 0; s < 8; ++s) acc[s] = z;
#pragma unroll
            for (int s = 0; s < 8; ++s) {
                if (s < cm) {
#pragma unroll
                    for (int ip = 0; ip < 4; ++ip) {
                        f32x4 h4 = *(const f32x4*)(hbufc + (s << 12) + (rb << 6) +
                                                   (((ip ^ (rb & 3))) << 4));
#pragma unroll
                        for (int t4 = 0; t4 < 4; ++t4)
                            acc[s] += h4[t4] * wv[ip * 4 + t4];
                    }
                }
            }
            // reduce over 8 row-blocks within each wave (lane bits 3..5)
#pragma unroll
            for (int s = 0; s < 8; ++s) {
                if (s < cm) {
                    f32x4 v = acc[s];
                    v += shx4(v, 8);
                    v += shx4(v, 16);
                    v += shx4(v, 32);
                    if ((tid & 56) == 0) part[s][w][cq] = v;
                }
            }
            __syncthreads();
            // final reduce over 8 waves + block-private scatter (workgroup-scope atomics)
            if (tid < (cm << 5)) {
                int s = tid >> 5, c = tid & 31;
                int cq2 = c >> 2, j = c & 3;
                float sum = 0.f;
#pragma unroll
                for (int w8 = 0; w8 < 8; ++w8) sum += part[s][w8][cq2][j];
                int t = nd[s0 + ch + s];
                int p = par[t];
                if (c < 24) {
                    atomAddWg(iou + (size_t)p * 3072 + (c >> 3) * 1024 + d0 + (c & 7), sum);
                } else {
                    int d = d0 + (c & 7);
                    float fv = sigm(sum + fxp[((size_t)t << 10) + d]);
                    float cv = cws[((size_t)t << 10) + d];
                    atomAddWg(sfc + (((size_t)p) << 10) + d, fv * cv);
                }
            }
            __syncthreads();
        }
    }
}

// ---------------- launcher ----------------
extern "C" void kernel_launch(void* const* d_in, const int* in_sizes, int n_in,
                              void* d_out, int out_size, void* d_ws, size_t ws_size,
                              hipStream_t stream) {
    const float* inputs = (const float*)d_in[0];
    const int* parent   = (const int*)d_in[1];
    const float* Wioux  = (const float*)d_in[2];
    const float* bioux  = (const float*)d_in[3];
    const float* Wiouh  = (const float*)d_in[4];
    const float* biouh  = (const float*)d_in[5];
    const float* Wfx    = (const float*)d_in[6];
    const float* bfx    = (const float*)d_in[7];
    const float* Wfh    = (const float*)d_in[8];
    const float* bfh    = (const float*)d_in[9];
    float* outf = (float*)d_out;
    char* ws = (char*)d_ws;

    ushort_t* aext   = (ushort_t*)(ws + OFF_AEXT);
    ushort_t* bt     = (ushort_t*)(ws + OFF_BT);
    float* iou       = (float*)(ws + OFF_IOU);
    float* fx        = (float*)(ws + OFF_FX);
    float* fxp       = (float*)(ws + OFF_FXP);
    float* sfc       = (float*)(ws + OFF_SFC);
    float* cws       = (float*)(ws + OFF_CWS);
    unsigned* g_nodes = (unsigned*)(ws + OFF_NODES);
    unsigned* g_start = (unsigned*)(ws + OFF_START);
    unsigned* g_nlev  = (unsigned*)(ws + OFF_NLEV);
    unsigned* cnt     = (unsigned*)(ws + OFF_CNT);

    k_build_aext<<<dim3(4096), dim3(256), 0, stream>>>(inputs, aext);
    k_build_bt<<<dim3(16, 64), dim3(256), 0, stream>>>(Wioux, Wfx, bt);
    k_sched<<<dim3(1), dim3(64), 0, stream>>>(parent, g_nodes, g_start, g_nlev);
    k_gemm<<<dim3(32, 32), dim3(256), 0, stream>>>(aext, bt, bioux, biouh, bfx, iou, fx);
    k_fxp<<<dim3(4097), dim3(256), 0, stream>>>(parent, fx, bfh, fxp, sfc, cnt);
    k_tree<<<dim3(NBLK), dim3(512), 0, stream>>>(Wiouh, Wfh, parent, iou, sfc, cws, fxp,
                                                 g_nodes, g_start, g_nlev, cnt, outf);
}

// Round 4
// 10584.932 us; speedup vs baseline: 1.2566x; 1.2055x over previous
//
#include <hip/hip_runtime.h>
#include <stdint.h>

typedef __attribute__((ext_vector_type(4))) float f32x4;
typedef __attribute__((ext_vector_type(8))) short s16x8;
typedef __attribute__((ext_vector_type(4))) unsigned short u16x4;
typedef unsigned short ushort_t;

#define NN 4096
#define NBLK 256
#define RING 1024

// ---------------- workspace byte offsets ----------------
#define OFF_AEXT   0ull                        // bf16 [4096][3072] (dead after k_gemm)
#define OFF_FLAGS  0ull                        // u32 [4100][256] = 4.2MB, aliases AEXT
#define OFF_BT     25165824ull                 // bf16 [4096][3072]
#define OFF_IOU    50331648ull                 // f32  [4097][3072]
#define OFF_FX     100675584ull                // f32  [4096][1024]
#define OFF_FXP    117452800ull                // f32  [4096][1024]
#define OFF_SFC    134230016ull                // f32  [4097][1024]
#define OFF_CWS    151011328ull                // f32  [4096][1024]
#define OFF_NODES  167788544ull                // u32  [4096]
#define OFF_START  (OFF_NODES + 16384ull)      // u32  [4100]
#define OFF_MISC   (OFF_START + 16400ull)      // u32  [4]: nlev, ring_ok
#define OFF_PAR16  (OFF_MISC + 16ull)          // u16  [4096]

// ---------------- helpers ----------------
__device__ __forceinline__ ushort_t f2bf(float f) {
    unsigned u = __float_as_uint(f);
    unsigned r = (u + 0x7FFFu + ((u >> 16) & 1u)) >> 16;
    return (ushort_t)r;
}
__device__ __forceinline__ float bf2f(ushort_t b) {
    return __uint_as_float(((unsigned)b) << 16);
}
__device__ __forceinline__ float sigm(float x) { return 1.0f / (1.0f + __expf(-x)); }
__device__ __forceinline__ float tanh_f(float x) {
    float e = __expf(-2.0f * fabsf(x));
    float t = (1.0f - e) / (1.0f + e);
    return copysignf(t, x);
}
// agent-scope (LLC) ops: ONLY for cross-block data (h, flags)
__device__ __forceinline__ unsigned long long ld_dev64(const void* p) {
    return __hip_atomic_load((const unsigned long long*)p, __ATOMIC_RELAXED,
                             __HIP_MEMORY_SCOPE_AGENT);
}
__device__ __forceinline__ void st_dev(float* p, float v) {
    __hip_atomic_store(p, v, __ATOMIC_RELAXED, __HIP_MEMORY_SCOPE_AGENT);
}
// workgroup-scope atomic add on block-private global data (fallback path only)
__device__ __forceinline__ void atomAddWg(float* p, float v) {
    __hip_atomic_fetch_add(p, v, __ATOMIC_RELAXED, __HIP_MEMORY_SCOPE_WORKGROUP);
}
__device__ __forceinline__ void gload16(const void* g, void* l) {
    __builtin_amdgcn_global_load_lds((const __attribute__((address_space(1))) unsigned*)g,
                                     (__attribute__((address_space(3))) unsigned*)l, 16, 0, 0);
}
__device__ __forceinline__ f32x4 shx4(f32x4 v, int m) {
    f32x4 r;
    r[0] = __shfl_xor(v[0], m); r[1] = __shfl_xor(v[1], m);
    r[2] = __shfl_xor(v[2], m); r[3] = __shfl_xor(v[3], m);
    return r;
}

// ---------------- kernel 1: build Aext (split-bf16 of inputs) ----------------
__global__ void k_build_aext(const float* __restrict__ inputs, ushort_t* __restrict__ aext) {
    int t = blockIdx.x;
    int k0 = threadIdx.x * 4;
    f32x4 v = *(const f32x4*)(inputs + (size_t)t * 1024 + k0);
    u16x4 hi, lo;
#pragma unroll
    for (int j = 0; j < 4; ++j) {
        float f = v[j];
        ushort_t hb = f2bf(f);
        float fr = f - bf2f(hb);
        hi[j] = hb; lo[j] = f2bf(fr);
    }
    size_t base = (size_t)t * 3072;
    *(u16x4*)(aext + base + k0)        = hi;
    *(u16x4*)(aext + base + 1024 + k0) = lo;
    *(u16x4*)(aext + base + 2048 + k0) = hi;
}

// ---------------- kernel 2: build B^T ext ----------------
__global__ void k_build_bt(const float* __restrict__ Wioux, const float* __restrict__ Wfx,
                           ushort_t* __restrict__ bt) {
    __shared__ float ld[64][65];
    int k0 = blockIdx.x * 64, n0 = blockIdx.y * 64;
    const float* src; int scol, sstr;
    if (n0 < 3072) { src = Wioux; scol = n0; sstr = 3072; }
    else           { src = Wfx;   scol = n0 - 3072; sstr = 1024; }
    int tid = threadIdx.x;
    int nl = tid & 63, kh = tid >> 6;
#pragma unroll
    for (int i = 0; i < 16; ++i) {
        int kl = kh * 16 + i;
        ld[kl][nl] = src[(size_t)(k0 + kl) * sstr + scol + nl];
    }
    __syncthreads();
    int nl2 = tid >> 2, kq = tid & 3;
#pragma unroll
    for (int i2 = 0; i2 < 4; ++i2) {
        int kb = kq * 16 + i2 * 4;
        u16x4 hi, lo;
#pragma unroll
        for (int j = 0; j < 4; ++j) {
            float f = ld[kb + j][nl2];
            ushort_t hb = f2bf(f);
            hi[j] = hb; lo[j] = f2bf(f - bf2f(hb));
        }
        size_t ob = (size_t)(n0 + nl2) * 3072 + k0 + kb;
        *(u16x4*)(bt + ob)        = hi;
        *(u16x4*)(bt + ob + 1024) = hi;
        *(u16x4*)(bt + ob + 2048) = lo;
    }
}

// ---------------- kernel 3: ALAP level schedule + ring-window check (1 wave) ----------------
__global__ void k_sched(const int* __restrict__ parent, unsigned* __restrict__ g_nodes,
                        unsigned* __restrict__ g_start, unsigned* __restrict__ g_misc,
                        ushort_t* __restrict__ par16_g) {
    volatile __shared__ unsigned short d16[4096];
    __shared__ unsigned short par16[4096];
    __shared__ unsigned short lv16[4096];
    __shared__ unsigned cnts[4100], curs[4100], mni[4100], mxi[4100];
    __shared__ unsigned sh_maxd;
    int lane = threadIdx.x; // 0..63
    for (int i = lane; i < 4096; i += 64) {
        d16[i] = 0xFFFFu;
        int p = parent[i];
        par16[i] = (ushort_t)p;
        par16_g[i] = (ushort_t)p;
    }
    for (int i = lane; i < 4100; i += 64) { cnts[i] = 0; mni[i] = 0xFFFFFFFFu; mxi[i] = 0; }
    __syncthreads();
    if (lane == 0) d16[4095] = 0;
    __syncthreads();
    // root-distance via descending-block fixpoint (parent index > own index)
    for (int base = 4032; base >= 0; base -= 64) {
        int t = base + lane;
        int iter = 0;
        while (iter++ < 80) {
            bool ch = false;
            if (t != 4095 && d16[t] == 0xFFFFu) {
                int p = par16[t];
                unsigned short dp = d16[p];
                if (dp != 0xFFFFu) { d16[t] = (unsigned short)(dp + 1); ch = true; }
            }
            if (!__any(ch)) break;
        }
        __syncthreads();
    }
    unsigned mx = 0;
    for (int i = lane; i < 4096; i += 64) mx = max(mx, (unsigned)d16[i]);
#pragma unroll
    for (int o = 32; o; o >>= 1) mx = max(mx, (unsigned)__shfl_xor((int)mx, o));
    if (lane == 0) sh_maxd = mx;
    __syncthreads();
    unsigned maxd = sh_maxd;
    // s = maxd - d  (ALAP level): parent is exactly one level above child
    for (int i = lane; i < 4096; i += 64) {
        unsigned s = maxd - (unsigned)d16[i];
        lv16[i] = (ushort_t)s;
        atomicAdd(&cnts[s], 1u);
        atomicMin(&mni[s], (unsigned)i);
        atomicMax(&mxi[s], (unsigned)i);
    }
    __syncthreads();
    // exclusive prefix sum of cnts
    unsigned carry = 0;
    for (int base = 0; base < 4100; base += 64) {
        int i = base + lane;
        unsigned v = (i < 4100) ? cnts[i] : 0u;
        unsigned orig = v;
#pragma unroll
        for (int o = 1; o < 64; o <<= 1) {
            unsigned n = __shfl_up(v, o);
            if (lane >= o) v += n;
        }
        unsigned excl = carry + v - orig;
        if (i < 4100) { curs[i] = excl; g_start[i] = excl; }
        carry += (unsigned)__shfl((int)v, 63);
    }
    __syncthreads();
    for (int i = lane; i < 4096; i += 64) {
        unsigned s = lv16[i];
        unsigned slot = atomicAdd(&curs[s], 1u);
        g_nodes[slot] = (unsigned)i;
    }
    // ring-window check over adjacent level pairs
    unsigned wm = 0;
    for (unsigned L = lane; L <= maxd; L += 64) {
        unsigned lo = mni[L], hi = mxi[L];
        if (L + 1 <= maxd) { lo = min(lo, mni[L + 1]); hi = max(hi, mxi[L + 1]); }
        wm = max(wm, hi - lo);
    }
#pragma unroll
    for (int o = 32; o; o >>= 1) wm = max(wm, (unsigned)__shfl_xor((int)wm, o));
    if (lane == 0) { g_misc[0] = maxd + 1; g_misc[1] = (wm <= (unsigned)(RING - 1)) ? 1u : 0u; }
}

// ---------------- kernel 4: split-bf16 MFMA GEMM ----------------
__launch_bounds__(256)
__global__ void k_gemm(const ushort_t* __restrict__ A, const ushort_t* __restrict__ B,
                       const float* __restrict__ bioux, const float* __restrict__ biouh,
                       const float* __restrict__ bfx,
                       float* __restrict__ iou, float* __restrict__ fx) {
    __shared__ ushort_t As[128 * 32];
    __shared__ ushort_t Bs[128 * 32];
    int tid = threadIdx.x;
    int w = tid >> 6, l = tid & 63;
    int m0 = blockIdx.x * 128, n0 = blockIdx.y * 128;
    int wr = w >> 1, wc = w & 1;
    f32x4 acc[4][4];
    f32x4 z = {0.f, 0.f, 0.f, 0.f};
#pragma unroll
    for (int a = 0; a < 4; ++a)
#pragma unroll
        for (int b = 0; b < 4; ++b) acc[a][b] = z;

    for (int k0 = 0; k0 < 3072; k0 += 32) {
        __syncthreads();
#pragma unroll
        for (int i = 0; i < 2; ++i) {
            int qb = i * 256 + w * 64;
            int q = qb + l;
            int row = q >> 2, ksp = q & 3;
            int ksl = ksp ^ (row & 3);
            gload16(A + (size_t)(m0 + row) * 3072 + k0 + ksl * 8, (char*)As + qb * 16);
            gload16(B + (size_t)(n0 + row) * 3072 + k0 + ksl * 8, (char*)Bs + qb * 16);
        }
        __syncthreads();
        s16x8 av[4], bv[4];
#pragma unroll
        for (int fr = 0; fr < 4; ++fr) {
            int ra = wr * 64 + fr * 16 + (l & 15);
            av[fr] = *(const s16x8*)((const char*)As + ra * 64 + ((((l >> 4) ^ (ra & 3)) & 3) << 4));
            int rb = wc * 64 + fr * 16 + (l & 15);
            bv[fr] = *(const s16x8*)((const char*)Bs + rb * 64 + ((((l >> 4) ^ (rb & 3)) & 3) << 4));
        }
#pragma unroll
        for (int fr = 0; fr < 4; ++fr)
#pragma unroll
            for (int fc = 0; fc < 4; ++fc)
                acc[fr][fc] = __builtin_amdgcn_mfma_f32_16x16x32_bf16(av[fr], bv[fc], acc[fr][fc], 0, 0, 0);
    }
#pragma unroll
    for (int fc = 0; fc < 4; ++fc) {
        int col = n0 + wc * 64 + fc * 16 + (l & 15);
        bool isiou = col < 3072;
        float badd = isiou ? (bioux[col] + biouh[col]) : bfx[col - 3072];
#pragma unroll
        for (int fr = 0; fr < 4; ++fr) {
            int r0 = m0 + wr * 64 + fr * 16 + ((l >> 4) << 2);
#pragma unroll
            for (int jj = 0; jj < 4; ++jj) {
                float v2 = acc[fr][fc][jj] + badd;
                if (isiou) iou[(size_t)(r0 + jj) * 3072 + col] = v2;
                else       fx[(size_t)(r0 + jj) * 1024 + (col - 3072)] = v2;
            }
        }
    }
}

// ---------------- kernel 5: fxp = bfh + fx[parent]; zero sum_fc ----------------
__global__ void k_fxp(const int* __restrict__ parent, const float* __restrict__ fx,
                      const float* __restrict__ bfh, float* __restrict__ fxp,
                      float* __restrict__ sfc) {
    int t = blockIdx.x;
    int d = threadIdx.x * 4;
    f32x4 z = {0.f, 0.f, 0.f, 0.f};
    if (t < 4096) {
        int p = parent[t];
        f32x4 add = (p < 4096) ? *(const f32x4*)(fx + ((size_t)p << 10) + d) : z;
        f32x4 bv = *(const f32x4*)(bfh + d);
        *(f32x4*)(fxp + ((size_t)t << 10) + d) = bv + add;
        *(f32x4*)(sfc + ((size_t)t << 10) + d) = z;
    } else {
        *(f32x4*)(sfc + ((size_t)t << 10) + d) = z;
    }
}

// ---------------- kernel 5b: zero the flag array ----------------
__global__ void k_zero(uint4* __restrict__ p, int n4) {
    int i = blockIdx.x * blockDim.x + threadIdx.x;
    uint4 z = {0u, 0u, 0u, 0u};
    for (; i < n4; i += gridDim.x * blockDim.x) p[i] = z;
}

// ---------------- kernel 6: persistent ALAP-level Tree-LSTM, LDS-ring aggregates ----------------
// 256 blocks x 512 threads; block b owns h-dims d0=4b..4b+3 (16 W-columns register-resident).
// Cross-block (LLC, cache-bypass ops): outf(h), flags. Everything else LDS or read-only.
__launch_bounds__(512, 1)
__global__ void k_tree(const float* __restrict__ Wiouh, const float* __restrict__ Wfh,
                       float* iou, float* sfc, float* cws,
                       const float* __restrict__ fxp,
                       const unsigned* __restrict__ g_nodes, const unsigned* __restrict__ g_start,
                       const unsigned* __restrict__ g_misc,
                       unsigned* flags, float* outf, const ushort_t* __restrict__ par16) {
    __shared__ __align__(16) float ring[RING][20];  // 80KB: 0-11 iou, 12-15 sum_fc, 16-19 c
    __shared__ __align__(16) float hbuf[8][1024];   // 32KB h staging (bit4^bit7 swizzle)
    __shared__ f32x4 part[8][8][4];                 // 4KB
    __shared__ ushort_t nd[4096];                   // 8KB level-ordered node ids
    __shared__ ushort_t par[4096];                  // 8KB
    __shared__ unsigned st[4100];                   // 16.4KB level starts

    int tid = threadIdx.x;
    int bid = blockIdx.x;
    int lane = tid & 63, w = tid >> 6;
    int d0 = bid << 2;                 // own 4 h-dims
    int rc = tid >> 2, cq = tid & 3;   // 128 row-chunks x 4 col-quads

    for (int i = tid; i < 4096; i += 512) nd[i] = (ushort_t)g_nodes[i];
    for (int i = tid; i < 4096; i += 512) par[i] = par16[i];
    for (int i = tid; i < 4100; i += 512) st[i] = g_start[i];
    for (int i = tid; i < RING * 20; i += 512) ((float*)ring)[i] = 0.f;

    unsigned nlev = g_misc[0];
    bool ringok = (g_misc[1] != 0u);
    if (nlev > 4096u) nlev = 4096u;

    // register-resident weights: 8 rows x 4 cols per thread (32 VGPRs)
    f32x4 wv[8];
    {
        const float* wb; size_t strd; int coff;
        if (cq < 3) { wb = Wiouh; strd = 3072; coff = cq * 1024 + d0; }
        else        { wb = Wfh;   strd = 1024; coff = d0; }
#pragma unroll
        for (int r8 = 0; r8 < 8; ++r8)
            wv[r8] = *(const f32x4*)(wb + (size_t)(rc * 8 + r8) * strd + coff);
    }
    __syncthreads();

    for (unsigned L = 0; L < nlev; ++L) {
        unsigned s0 = st[L], s1 = st[L + 1];
        if (s0 > 4096u) s0 = 4096u;
        if (s1 > 4096u) s1 = 4096u;
        if (s1 < s0) s1 = s0;
        int m = (int)(s1 - s0);

        // ---- phase E: gates for level-L nodes, own 4 dims ----
        for (int idx = tid; idx < (m << 2); idx += 512) {
            int s = idx >> 2, j = idx & 3;
            int t = nd[s0 + s];
            int d = d0 + j;
            int slot = t & (RING - 1);
            size_t b3 = (size_t)t * 3072 + d;
            float ri, ro, ru, rf;
            if (ringok) {
                ri = ring[slot][j];     ro = ring[slot][4 + j];
                ru = ring[slot][8 + j]; rf = ring[slot][12 + j];
                ring[slot][j] = 0.f; ring[slot][4 + j] = 0.f;
                ring[slot][8 + j] = 0.f; ring[slot][12 + j] = 0.f;
            } else {
                ri = ro = ru = 0.f;
                rf = sfc[((size_t)t << 10) + d];
            }
            float vi = iou[b3] + ri;
            float vo = iou[b3 + 1024] + ro;
            float vu = iou[b3 + 2048] + ru;
            float cc = sigm(vi) * tanh_f(vu) + rf;
            float hh = sigm(vo) * tanh_f(cc);
            if (ringok) ring[slot][16 + j] = cc;
            else        cws[((size_t)t << 10) + d] = cc;
            st_dev(outf + ((size_t)t << 10) + d, hh);   // publish h (LLC)
        }
        // drain h stores, then signal
        asm volatile("s_waitcnt vmcnt(0)" ::: "memory");
        __syncthreads();
        if (tid == 0)
            __hip_atomic_store(flags + (size_t)L * 256 + bid, 1u,
                               __ATOMIC_RELAXED, __HIP_MEMORY_SCOPE_AGENT);
        if (tid < 128) {
            const unsigned long long* fp =
                (const unsigned long long*)(flags + (size_t)L * 256) + tid;
            int sp = 0;
            while (true) {
                unsigned long long v = __hip_atomic_load(fp, __ATOMIC_RELAXED,
                                                         __HIP_MEMORY_SCOPE_AGENT);
                if ((unsigned)v != 0u && (unsigned)(v >> 32) != 0u) break;
                __builtin_amdgcn_s_sleep(1);
                if (++sp > (1 << 17)) break;
            }
        }
        __syncthreads();

        // ---- phase M: W^T h contributions into level-(L+1) ring slots ----
        for (int ch = 0; ch < m; ch += 8) {
            int cm = min(8, m - ch);
            int items = cm << 9;   // cm*512 u64s
            for (int q = tid; q < items; q += 512) {
                int s = q >> 9, r = q & 511;
                int t = nd[s0 + ch + s];
                unsigned long long v = ld_dev64(outf + ((size_t)t << 10) + (r << 1));
                *(unsigned long long*)((char*)&hbuf[s][0] +
                    (((unsigned)(r << 3)) ^ ((((unsigned)r >> 4) & 1u) << 4))) = v;
            }
            __syncthreads();
            f32x4 acc[8];
            f32x4 z = {0.f, 0.f, 0.f, 0.f};
#pragma unroll
            for (int s = 0; s < 8; ++s) acc[s] = z;
#pragma unroll
            for (int s = 0; s < 8; ++s) {
                if (s < cm) {
#pragma unroll
                    for (int ip = 0; ip < 2; ++ip) {
                        // physical bit4 = ip ^ (addr bit7) ; logically this is rows ip*4..ip*4+3
                        f32x4 h4 = *(const f32x4*)((char*)&hbuf[s][0] +
                                     (rc << 5) + (((ip ^ ((rc >> 2) & 1)) & 1) << 4));
#pragma unroll
                        for (int j4 = 0; j4 < 4; ++j4)
                            acc[s] += h4[j4] * wv[ip * 4 + j4];
                    }
                }
            }
            // reduce over 16 row-chunk groups within wave (lane bits 2..5)
#pragma unroll
            for (int s = 0; s < 8; ++s) {
                if (s < cm) {
                    f32x4 v = acc[s];
                    v += shx4(v, 4);
                    v += shx4(v, 8);
                    v += shx4(v, 16);
                    v += shx4(v, 32);
                    if ((lane & 60) == 0) part[s][w][cq] = v;
                }
            }
            __syncthreads();
            int nsc = cm << 4;
            bool lastch = (ch + 8 >= m);
            if (tid < nsc) {
                int s = tid >> 4, c = tid & 15, cq2 = c >> 2, j = c & 3;
                float sum = 0.f;
#pragma unroll
                for (int w8 = 0; w8 < 8; ++w8) sum += part[s][w8][cq2][j];
                int t = nd[s0 + ch + s];
                int p = par[t];
                if (c < 12) {
                    if (ringok) { if (p < 4096) atomicAdd(&ring[p & (RING - 1)][c], sum); }
                    else atomAddWg(iou + (size_t)p * 3072 + cq2 * 1024 + d0 + j, sum);
                } else {
                    int d = d0 + j;
                    float fv = sigm(sum + fxp[((size_t)t << 10) + d]);
                    float cv = ringok ? ring[t & (RING - 1)][16 + j]
                                      : cws[((size_t)t << 10) + d];
                    float pr = fv * cv;
                    if (ringok) { if (p < 4096) atomicAdd(&ring[p & (RING - 1)][12 + j], pr); }
                    else atomAddWg(sfc + ((size_t)p << 10) + d, pr);
                }
            } else if (ringok && lastch && L + 1 < nlev) {
                // prefetch next level's iou_x / fxp lines into cache (read-only data)
                int idx = tid - nsc;
                unsigned s0n = st[L + 1];
                int m2 = (int)(st[L + 2] - s0n);
                int s2 = idx >> 2, g = idx & 3;
                if (s2 < m2) {
                    int t2 = nd[s0n + s2];
                    float v;
                    if (g < 3) v = iou[(size_t)t2 * 3072 + g * 1024 + d0];
                    else       v = fxp[((size_t)t2 << 10) + d0];
                    asm volatile("" :: "v"(v));
                }
            }
            __syncthreads();
        }
    }
}

// ---------------- launcher ----------------
extern "C" void kernel_launch(void* const* d_in, const int* in_sizes, int n_in,
                              void* d_out, int out_size, void* d_ws, size_t ws_size,
                              hipStream_t stream) {
    const float* inputs = (const float*)d_in[0];
    const int* parent   = (const int*)d_in[1];
    const float* Wioux  = (const float*)d_in[2];
    const float* bioux  = (const float*)d_in[3];
    const float* Wiouh  = (const float*)d_in[4];
    const float* biouh  = (const float*)d_in[5];
    const float* Wfx    = (const float*)d_in[6];
    const float* bfx    = (const float*)d_in[7];
    const float* Wfh    = (const float*)d_in[8];
    const float* bfh    = (const float*)d_in[9];
    float* outf = (float*)d_out;
    char* ws = (char*)d_ws;

    ushort_t* aext    = (ushort_t*)(ws + OFF_AEXT);
    unsigned* flags   = (unsigned*)(ws + OFF_FLAGS);
    ushort_t* bt      = (ushort_t*)(ws + OFF_BT);
    float* iou        = (float*)(ws + OFF_IOU);
    float* fx         = (float*)(ws + OFF_FX);
    float* fxp        = (float*)(ws + OFF_FXP);
    float* sfc        = (float*)(ws + OFF_SFC);
    float* cws        = (float*)(ws + OFF_CWS);
    unsigned* g_nodes = (unsigned*)(ws + OFF_NODES);
    unsigned* g_start = (unsigned*)(ws + OFF_START);
    unsigned* g_misc  = (unsigned*)(ws + OFF_MISC);
    ushort_t* par16   = (ushort_t*)(ws + OFF_PAR16);

    k_build_aext<<<dim3(4096), dim3(256), 0, stream>>>(inputs, aext);
    k_build_bt<<<dim3(16, 64), dim3(256), 0, stream>>>(Wioux, Wfx, bt);
    k_sched<<<dim3(1), dim3(64), 0, stream>>>(parent, g_nodes, g_start, g_misc, par16);
    k_gemm<<<dim3(32, 32), dim3(256), 0, stream>>>(aext, bt, bioux, biouh, bfx, iou, fx);
    k_fxp<<<dim3(4097), dim3(256), 0, stream>>>(parent, fx, bfh, fxp, sfc);
    k_zero<<<dim3(512), dim3(256), 0, stream>>>((uint4*)flags, (4100 * 256) / 4);
    k_tree<<<dim3(NBLK), dim3(512), 0, stream>>>(Wiouh, Wfh, iou, sfc, cws, fxp,
                                                 g_nodes, g_start, g_misc, flags, outf, par16);
}